// Round 10
// baseline (693.032 us; speedup 1.0000x reference)
//
#include <hip/hip_runtime.h>
#include <hip/hip_bf16.h>

typedef __bf16 bf16_t;
typedef __attribute__((ext_vector_type(8))) __bf16 bf16x8;
typedef __attribute__((ext_vector_type(4))) float f32x4;

#define E_DIM 256
#define J_DIM 32
#define B_DIM 4096
#define M_DIM (B_DIM * J_DIM)
#define BK 32
#define LDA 40
#define LDB 40
#define LDU 264  // persistent U tile pad: row stride 528B -> uniform bank spread

#define XK_LDA (E_DIM + 4)  // fp32 xk tile pad: 32-way -> 4-way bank alias

// load 8 consecutive fp32, convert to bf16x8 (RNE)
__device__ inline bf16x8 cvt8(const float* __restrict__ p) {
    f32x4 a = *(const f32x4*)p;
    f32x4 b = *(const f32x4*)(p + 4);
    bf16x8 r;
    r[0] = (bf16_t)a[0]; r[1] = (bf16_t)a[1]; r[2] = (bf16_t)a[2]; r[3] = (bf16_t)a[3];
    r[4] = (bf16_t)b[0]; r[5] = (bf16_t)b[1]; r[6] = (bf16_t)b[2]; r[7] = (bf16_t)b[3];
    return r;
}

// ---------------------------------------------------------------------------
// fused: [0,512): xk[b][j] = <x_b, k_j>  (8 b per block, padded LDS)
//        [512,544): vkb[j][f] = bias[f] + sum_e V[f,e]*keys[j,e]
// (unchanged from round 6)
// ---------------------------------------------------------------------------
__global__ __launch_bounds__(256) void xkvkb_kernel(
    const float* __restrict__ x, const float* __restrict__ keys,
    const float* __restrict__ V, const float* __restrict__ bias,
    float* __restrict__ xk, float* __restrict__ vkb) {
    __shared__ float smem[(J_DIM + 8) * XK_LDA];   // 40*260 fp32 = 41.6 KB
    int tid = threadIdx.x, bid = blockIdx.x;
    if (bid < 512) {
        float* sK = smem;                          // [32][XK_LDA]
        float* sX = smem + J_DIM * XK_LDA;         // [8][XK_LDA]
        int b0 = bid * 8;
#pragma unroll
        for (int it = 0; it < 8; ++it) {
            int t = it * 256 + tid;
            int r = t >> 6, c = (t & 63) * 4;
            *(f32x4*)(sK + r * XK_LDA + c) = *(const f32x4*)(keys + (size_t)r * E_DIM + c);
        }
#pragma unroll
        for (int it = 0; it < 2; ++it) {
            int t = it * 256 + tid;
            int r = t >> 6, c = (t & 63) * 4;
            *(f32x4*)(sX + r * XK_LDA + c) =
                *(const f32x4*)(x + (size_t)b0 * E_DIM + (size_t)r * E_DIM + c);
        }
        __syncthreads();
        int j = tid & 31, bl = tid >> 5;
        float acc = 0.f;
        for (int e = 0; e < E_DIM; e += 4) {
            f32x4 xv = *(const f32x4*)(sX + bl * XK_LDA + e);
            f32x4 kv = *(const f32x4*)(sK + j * XK_LDA + e);
#pragma unroll
            for (int i = 0; i < 4; ++i) acc += xv[i] * kv[i];
        }
        xk[(size_t)(b0 + bl) * J_DIM + j] = acc;
    } else {
        int j = bid - 512, f = tid;
        float* sk = smem;
        sk[f] = keys[(size_t)j * E_DIM + f];
        __syncthreads();
        float acc = bias[f];
        for (int e = 0; e < E_DIM; e += 4) {
            f32x4 vv = *(const f32x4*)(V + (size_t)f * E_DIM + e);
#pragma unroll
            for (int i = 0; i < 4; ++i) acc += vv[i] * sk[e + i];
        }
        vkb[(size_t)j * E_DIM + f] = acc;
    }
}

// ---------------------------------------------------------------------------
// wx[b][f] = sum_e W[f,e]*x[b,e] — unchanged from round 6 (well-shaped:
// 256 blocks = 64 m-tiles x 4 n-tiles, 64x64).
// ---------------------------------------------------------------------------
__global__ __launch_bounds__(256) void wx_kernel(const float* __restrict__ x,
                                                 const float* __restrict__ W,
                                                 float* __restrict__ wx) {
    __shared__ __align__(16) bf16_t sA[64][LDA];
    __shared__ __align__(16) bf16_t sBw[64][LDB];
    int tid = threadIdx.x;
    int w = tid >> 6, lane = tid & 63, quad = lane >> 4, l15 = lane & 15;
    int m0 = (blockIdx.x >> 2) * 64, n0 = (blockIdx.x & 3) * 64;
    f32x4 acc[4];
#pragma unroll
    for (int nt = 0; nt < 4; ++nt)
#pragma unroll
        for (int r = 0; r < 4; ++r) acc[nt][r] = 0.f;
    int arow = tid >> 2, akk = (tid & 3) * 8;
    for (int kc = 0; kc < 8; ++kc) {
        int k0 = kc * BK;
        __syncthreads();
        *(bf16x8*)(&sA[arow][akk]) = cvt8(x + (size_t)(m0 + arow) * E_DIM + k0 + akk);
        *(bf16x8*)(&sBw[arow][akk]) = cvt8(W + (size_t)(n0 + arow) * E_DIM + k0 + akk);
        __syncthreads();
        bf16x8 af = *(const bf16x8*)(&sA[w * 16 + l15][quad * 8]);
#pragma unroll
        for (int nt = 0; nt < 4; ++nt) {
            bf16x8 bfr = *(const bf16x8*)(&sBw[nt * 16 + l15][quad * 8]);
            acc[nt] = __builtin_amdgcn_mfma_f32_16x16x32_bf16(af, bfr, acc[nt], 0, 0, 0);
        }
    }
#pragma unroll
    for (int nt = 0; nt < 4; ++nt)
#pragma unroll
        for (int r = 0; r < 4; ++r)
            wx[(size_t)(m0 + w * 16 + quad * 4 + r) * E_DIM + n0 + nt * 16 + l15] =
                acc[nt][r];
}

// ---------------------------------------------------------------------------
// main: persistent-U, barrier-free K-loop.
//   Prologue: stage ALL of U (bf16, [256][LDU] = 132 KB) into LDS once —
//   8192 bf16x8 slots, 16 per thread (round-9 bug: only 2/16 were staged).
//   Then 4 m-tiles of 128 rows; per kc: A-fragment + gate-dot operands loaded
//   DIRECTLY from global (32B/lane contiguous, r1-validated pattern),
//   16 MFMA read B-frags from resident sU. No __syncthreads after prologue:
//   8 independent waves/CU, compiler pipelines loads freely (no vmcnt(0)
//   barrier drain). gate = sigmoid(<x,s>_fp32 + xk). Epilogue unchanged.
// ---------------------------------------------------------------------------
__global__ __launch_bounds__(512) void memcell_kernel(
    const float* __restrict__ x, const float* __restrict__ state,
    const float* __restrict__ U, const float* __restrict__ wx,
    const float* __restrict__ xk, const float* __restrict__ vkb,
    float* __restrict__ out) {
    __shared__ __align__(16) bf16_t sU[E_DIM][LDU];   // 135168 B
    int tid = threadIdx.x;
    int w = tid >> 6, lane = tid & 63, quad = lane >> 4, l15 = lane & 15;

    // prologue: stage whole U as bf16. 256 rows x 32 slots = 8192 slots,
    // 16 per thread, tid-consecutive slots -> coalesced 16B global reads.
#pragma unroll
    for (int it = 0; it < 16; ++it) {
        int s = it * 512 + tid;
        int n = s >> 5, kk = (s & 31) * 8;
        *(bf16x8*)(&sU[n][kk]) = cvt8(U + (size_t)n * E_DIM + kk);
    }
    __syncthreads();

    int mbase = blockIdx.x * 512;           // 4 m-tiles of 128 rows
    for (int mt = 0; mt < 4; ++mt) {
        int m0 = mbase + mt * 128;
        int bw = (m0 >> 5) + (w >> 1);      // one b per wave-half
        const float* sp = state + (size_t)(m0 + w * 16 + l15) * E_DIM + quad * 8;
        const float* xp = x + (size_t)bw * E_DIM + quad * 8;
        f32x4 acc[16];
#pragma unroll
        for (int nt = 0; nt < 16; ++nt)
#pragma unroll
            for (int r = 0; r < 4; ++r) acc[nt][r] = 0.f;
        float gdot = 0.f;
        for (int kc = 0; kc < 8; ++kc) {
            int k0 = kc * BK;
            f32x4 a0  = *(const f32x4*)(sp + k0);
            f32x4 a1  = *(const f32x4*)(sp + k0 + 4);
            f32x4 xv0 = *(const f32x4*)(xp + k0);
            f32x4 xv1 = *(const f32x4*)(xp + k0 + 4);
            bf16x8 af;
#pragma unroll
            for (int i = 0; i < 4; ++i) { af[i] = (bf16_t)a0[i]; af[4 + i] = (bf16_t)a1[i]; }
#pragma unroll
            for (int i = 0; i < 4; ++i) gdot += a0[i] * xv0[i];
#pragma unroll
            for (int i = 0; i < 4; ++i) gdot += a1[i] * xv1[i];
#pragma unroll
            for (int nt = 0; nt < 16; ++nt) {
                bf16x8 bfr = *(const bf16x8*)(&sU[nt * 16 + l15][k0 + quad * 8]);
                acc[nt] = __builtin_amdgcn_mfma_f32_16x16x32_bf16(af, bfr, acc[nt], 0, 0, 0);
            }
        }
        // reduce gate dot across quads (k was split quad-wise)
        gdot += __shfl_xor(gdot, 16);
        gdot += __shfl_xor(gdot, 32);
        float garg = gdot + xk[(size_t)bw * J_DIM + (w & 1) * 16 + l15];
        float gv = 1.f / (1.f + expf(-garg));
        float gate[4];
#pragma unroll
        for (int r = 0; r < 4; ++r) gate[r] = __shfl(gv, quad * 4 + r);
        // epilogue: C/D layout row = quad*4+r, col = nt*16+l15
        float sumsq[4] = {0.f, 0.f, 0.f, 0.f};
        const float* wxrow = wx + (size_t)bw * E_DIM;
#pragma unroll
        for (int nt = 0; nt < 16; ++nt) {
            int f = nt * 16 + l15;
            float wxf = wxrow[f];
#pragma unroll
            for (int r = 0; r < 4; ++r) {
                int rl = quad * 4 + r;
                int jidx = (w & 1) * 16 + rl;
                float c = acc[nt][r] + wxf + vkb[(size_t)jidx * E_DIM + f];
                c = fmaxf(c, 0.f);
                float sv = state[(size_t)(m0 + w * 16 + rl) * E_DIM + f]; // L2-hot
                float t = fmaf(gate[r], c, sv);
                acc[nt][r] = t;
                sumsq[r] += t * t;
            }
        }
        float rn[4];
#pragma unroll
        for (int r = 0; r < 4; ++r) {
            float s2 = sumsq[r];
            s2 += __shfl_xor(s2, 1);
            s2 += __shfl_xor(s2, 2);
            s2 += __shfl_xor(s2, 4);
            s2 += __shfl_xor(s2, 8);
            rn[r] = 1.f / (sqrtf(s2) + 1e-8f);
        }
#pragma unroll
        for (int nt = 0; nt < 16; ++nt)
#pragma unroll
            for (int r = 0; r < 4; ++r)
                out[(size_t)(m0 + w * 16 + quad * 4 + r) * E_DIM + nt * 16 + l15] =
                    acc[nt][r] * rn[r];
    }
}

extern "C" void kernel_launch(void* const* d_in, const int* in_sizes, int n_in,
                              void* d_out, int out_size, void* d_ws, size_t ws_size,
                              hipStream_t stream) {
    const float* x     = (const float*)d_in[0];
    const float* state = (const float*)d_in[1];
    const float* keys  = (const float*)d_in[2];
    const float* U     = (const float*)d_in[3];
    const float* V     = (const float*)d_in[4];
    const float* W     = (const float*)d_in[5];
    const float* bias  = (const float*)d_in[6];
    float* out = (float*)d_out;

    float* wsf = (float*)d_ws;
    float* wx  = wsf;                                   // 4096*256 fp32 = 4 MB
    float* xk  = wsf + (size_t)B_DIM * E_DIM;           // 4096*32  fp32 = 512 KB
    float* vkb = xk + (size_t)B_DIM * J_DIM;            // 32*256   fp32 = 32 KB

    xkvkb_kernel<<<544, 256, 0, stream>>>(x, keys, V, bias, xk, vkb);
    wx_kernel<<<256, 256, 0, stream>>>(x, W, wx);
    memcell_kernel<<<M_DIM / 512, 512, 0, stream>>>(x, state, U, wx, xk, vkb, out);
}

// Round 11
// 355.593 us; speedup vs baseline: 1.9490x; 1.9490x over previous
//
#include <hip/hip_runtime.h>
#include <hip/hip_bf16.h>

typedef __bf16 bf16_t;
typedef __attribute__((ext_vector_type(8))) __bf16 bf16x8;
typedef __attribute__((ext_vector_type(4))) __bf16 bf16x4;
typedef __attribute__((ext_vector_type(4))) float f32x4;

#define E_DIM 256
#define J_DIM 32
#define B_DIM 4096
#define M_DIM (B_DIM * J_DIM)
#define BM 64
#define BK 32
#define LDA 40   // bf16: BK + 8 pad (16B-aligned, spreads banks)
#define LDB 40
#define LDAF 33  // fp32: BK + 1 pad (max 2-way bank alias = free)

#define XK_LDA (E_DIM + 4)  // fp32 xk tile pad: 32-way -> 4-way bank alias

// load 8 consecutive fp32, convert to bf16x8 (RNE)
__device__ inline bf16x8 cvt8(const float* __restrict__ p) {
    f32x4 a = *(const f32x4*)p;
    f32x4 b = *(const f32x4*)(p + 4);
    bf16x8 r;
    r[0] = (bf16_t)a[0]; r[1] = (bf16_t)a[1]; r[2] = (bf16_t)a[2]; r[3] = (bf16_t)a[3];
    r[4] = (bf16_t)b[0]; r[5] = (bf16_t)b[1]; r[6] = (bf16_t)b[2]; r[7] = (bf16_t)b[3];
    return r;
}

// ---------------------------------------------------------------------------
// fused: [0,512): xk[b][j] = <x_b, k_j>  (8 b per block, padded LDS)
//        [512,576): U -> bf16 (RNE, same values as in-loop cvt8 — r4/r7 valid)
//        [576,608): vkb[j][f] = bias[f] + sum_e V[f,e]*keys[j,e]
// ---------------------------------------------------------------------------
__global__ __launch_bounds__(256) void xkvkb_kernel(
    const float* __restrict__ x, const float* __restrict__ keys,
    const float* __restrict__ U, const float* __restrict__ V,
    const float* __restrict__ bias,
    float* __restrict__ xk, float* __restrict__ vkb, bf16_t* __restrict__ Ubf) {
    __shared__ float smem[(J_DIM + 8) * XK_LDA];   // 40*260 fp32 = 41.6 KB
    int tid = threadIdx.x, bid = blockIdx.x;
    if (bid < 512) {
        float* sK = smem;                          // [32][XK_LDA]
        float* sX = smem + J_DIM * XK_LDA;         // [8][XK_LDA]
        int b0 = bid * 8;
#pragma unroll
        for (int it = 0; it < 8; ++it) {
            int t = it * 256 + tid;
            int r = t >> 6, c = (t & 63) * 4;
            *(f32x4*)(sK + r * XK_LDA + c) = *(const f32x4*)(keys + (size_t)r * E_DIM + c);
        }
#pragma unroll
        for (int it = 0; it < 2; ++it) {
            int t = it * 256 + tid;
            int r = t >> 6, c = (t & 63) * 4;
            *(f32x4*)(sX + r * XK_LDA + c) =
                *(const f32x4*)(x + (size_t)b0 * E_DIM + (size_t)r * E_DIM + c);
        }
        __syncthreads();
        int j = tid & 31, bl = tid >> 5;
        float acc = 0.f;
        for (int e = 0; e < E_DIM; e += 4) {
            f32x4 xv = *(const f32x4*)(sX + bl * XK_LDA + e);
            f32x4 kv = *(const f32x4*)(sK + j * XK_LDA + e);
#pragma unroll
            for (int i = 0; i < 4; ++i) acc += xv[i] * kv[i];
        }
        xk[(size_t)(b0 + bl) * J_DIM + j] = acc;
    } else if (bid < 576) {
        int idx = (bid - 512) * 1024 + tid * 4;
        f32x4 v = *(const f32x4*)(U + idx);
        bf16x4 o;
#pragma unroll
        for (int i = 0; i < 4; ++i) o[i] = (bf16_t)v[i];
        *(bf16x4*)(Ubf + idx) = o;
    } else {
        int j = bid - 576, f = tid;
        float* sk = smem;
        sk[f] = keys[(size_t)j * E_DIM + f];
        __syncthreads();
        float acc = bias[f];
        for (int e = 0; e < E_DIM; e += 4) {
            f32x4 vv = *(const f32x4*)(V + (size_t)f * E_DIM + e);
#pragma unroll
            for (int i = 0; i < 4; ++i) acc += vv[i] * sk[e + i];
        }
        vkb[(size_t)j * E_DIM + f] = acc;
    }
}

// ---------------------------------------------------------------------------
// wx[b][f] = sum_e W[f,e]*x[b,e] — unchanged from round 6 (well-shaped:
// 256 blocks = 64 m-tiles x 4 n-tiles, 64x64).
// ---------------------------------------------------------------------------
__global__ __launch_bounds__(256) void wx_kernel(const float* __restrict__ x,
                                                 const float* __restrict__ W,
                                                 float* __restrict__ wx) {
    __shared__ __align__(16) bf16_t sA[64][LDA];
    __shared__ __align__(16) bf16_t sBw[64][LDB];
    int tid = threadIdx.x;
    int w = tid >> 6, lane = tid & 63, quad = lane >> 4, l15 = lane & 15;
    int m0 = (blockIdx.x >> 2) * 64, n0 = (blockIdx.x & 3) * 64;
    f32x4 acc[4];
#pragma unroll
    for (int nt = 0; nt < 4; ++nt)
#pragma unroll
        for (int r = 0; r < 4; ++r) acc[nt][r] = 0.f;
    int arow = tid >> 2, akk = (tid & 3) * 8;
    for (int kc = 0; kc < 8; ++kc) {
        int k0 = kc * BK;
        __syncthreads();
        *(bf16x8*)(&sA[arow][akk]) = cvt8(x + (size_t)(m0 + arow) * E_DIM + k0 + akk);
        *(bf16x8*)(&sBw[arow][akk]) = cvt8(W + (size_t)(n0 + arow) * E_DIM + k0 + akk);
        __syncthreads();
        bf16x8 af = *(const bf16x8*)(&sA[w * 16 + l15][quad * 8]);
#pragma unroll
        for (int nt = 0; nt < 4; ++nt) {
            bf16x8 bfr = *(const bf16x8*)(&sBw[nt * 16 + l15][quad * 8]);
            acc[nt] = __builtin_amdgcn_mfma_f32_16x16x32_bf16(af, bfr, acc[nt], 0, 0, 0);
        }
    }
#pragma unroll
    for (int nt = 0; nt < 4; ++nt)
#pragma unroll
        for (int r = 0; r < 4; ++r)
            wx[(size_t)(m0 + w * 16 + quad * 4 + r) * E_DIM + n0 + nt * 16 + l15] =
                acc[nt][r];
}

// ---------------------------------------------------------------------------
// main: r6 (115 us) structure with ONE isolated change — the B-stage register
// round-trip is replaced by async global_load_lds (width 16) from Ubf into an
// UNPADDED sB[256][32], with both-sides XOR swizzle (G21):
//   stage source col-block = kk ^ ((row>>1)&3); read col-block = quad ^ swz.
// Rows 0..7 then hit 8 distinct bank-quads -> only a free 2-way alias (m136).
// A-stage (fp32->sAf + cvt->sA), barriers, gate dot, epilogue: IDENTICAL.
// ---------------------------------------------------------------------------
__global__ __launch_bounds__(256) void memcell_kernel(
    const float* __restrict__ x, const float* __restrict__ state,
    const bf16_t* __restrict__ Ubf, const float* __restrict__ wx,
    const float* __restrict__ xk, const float* __restrict__ vkb,
    float* __restrict__ out) {
    __shared__ __align__(16) bf16_t sA[BM][LDA];
    __shared__ __align__(16) bf16_t sB[E_DIM][32];  // UNPADDED: gll linear dest
    __shared__ __align__(16) float sAf[BM][LDAF];   // fp32 state tile (gate dot)
    __shared__ __align__(16) float sXf[2][E_DIM];   // fp32 x rows     (gate dot)
    int tid = threadIdx.x;
    int w = tid >> 6, lane = tid & 63, quad = lane >> 4, l15 = lane & 15;
    int m0 = blockIdx.x * BM;
    int b0 = m0 >> 5;                       // block covers b0, b0+1
    f32x4 acc[16];
#pragma unroll
    for (int nt = 0; nt < 16; ++nt)
#pragma unroll
        for (int r = 0; r < 4; ++r) acc[nt][r] = 0.f;
    float gdot = 0.f;
    if (tid < 64) {                          // stage the 2 x-rows (fp32)
        int bb = tid >> 5, p = tid & 31;
        f32x4 xa = *(const f32x4*)(x + (size_t)(b0 + bb) * E_DIM + p * 8);
        f32x4 xb = *(const f32x4*)(x + (size_t)(b0 + bb) * E_DIM + p * 8 + 4);
        *(f32x4*)(&sXf[bb][p * 8]) = xa;
        *(f32x4*)(&sXf[bb][p * 8 + 4]) = xb;
    }
    int arow = tid >> 2, akk = (tid & 3) * 8;
    // B-stage slot geometry (per kc): 1024 slots of 16B; thread handles 4.
    // slot s -> row = s>>2, kk = s&3; source col-block kk ^ ((row>>1)&3).
    bf16_t* lbase = &sB[0][0];
    int bswz = (l15 >> 1) & 3;               // read-side swizzle (uniform in nt)
    for (int kc = 0; kc < 8; ++kc) {
        int k0 = kc * BK;
        __syncthreads();
        {   // stage state tile: fp32 copy for gate dot + bf16 for MFMA
            const float* sp = state + (size_t)(m0 + arow) * E_DIM + k0 + akk;
            f32x4 a = *(const f32x4*)sp;
            f32x4 b = *(const f32x4*)(sp + 4);
            *(f32x4*)(&sAf[arow][akk]) = a;
            *(f32x4*)(&sAf[arow][akk + 4]) = b;
            bf16x8 r;
            r[0] = (bf16_t)a[0]; r[1] = (bf16_t)a[1]; r[2] = (bf16_t)a[2]; r[3] = (bf16_t)a[3];
            r[4] = (bf16_t)b[0]; r[5] = (bf16_t)b[1]; r[6] = (bf16_t)b[2]; r[7] = (bf16_t)b[3];
            *(bf16x8*)(&sA[arow][akk]) = r;
        }
#pragma unroll
        for (int it = 0; it < 4; ++it) {     // async B-stage: 4x gll width=16
            int s = it * 256 + tid;
            int n = s >> 2, kk = s & 3;
            int kksrc = kk ^ ((n >> 1) & 3);
            const bf16_t* g = Ubf + (size_t)n * E_DIM + k0 + kksrc * 8;
            __builtin_amdgcn_global_load_lds(
                (const __attribute__((address_space(1))) unsigned int*)g,
                (__attribute__((address_space(3))) unsigned int*)(lbase + s * 8),
                16, 0, 0);
        }
        __syncthreads();                     // vmcnt(0) drain: sA+sB visible
        // A-frag: row = w*16+l15 (wave owns 16 full rows), k = k0 + quad*8 + j
        bf16x8 af = *(const bf16x8*)(&sA[w * 16 + l15][quad * 8]);
#pragma unroll
        for (int i = 0; i < 8; ++i)
            gdot += sAf[w * 16 + l15][quad * 8 + i] * sXf[w >> 1][k0 + quad * 8 + i];
        int qs = (quad ^ bswz) * 8;          // swizzled B read column
#pragma unroll
        for (int nt = 0; nt < 16; ++nt) {
            bf16x8 bfr = *(const bf16x8*)(&sB[nt * 16 + l15][qs]);
            acc[nt] = __builtin_amdgcn_mfma_f32_16x16x32_bf16(af, bfr, acc[nt], 0, 0, 0);
        }
    }
    // reduce gate dot across quads (k was split quad-wise): lanes sharing l15
    gdot += __shfl_xor(gdot, 16);
    gdot += __shfl_xor(gdot, 32);
    int bw = b0 + (w >> 1);                 // one b per wave
    float garg = gdot + xk[(size_t)bw * J_DIM + (w & 1) * 16 + l15];
    float gv = 1.f / (1.f + expf(-garg));
    float gate[4];
#pragma unroll
    for (int r = 0; r < 4; ++r) gate[r] = __shfl(gv, quad * 4 + r);
    // epilogue: C/D layout row = quad*4+r, col = nt*16+l15
    float sumsq[4] = {0.f, 0.f, 0.f, 0.f};
    const float* wxrow = wx + (size_t)bw * E_DIM;
#pragma unroll
    for (int nt = 0; nt < 16; ++nt) {
        int f = nt * 16 + l15;
        float wxf = wxrow[f];
#pragma unroll
        for (int r = 0; r < 4; ++r) {
            int rl = quad * 4 + r;
            int jidx = (w & 1) * 16 + rl;
            float c = acc[nt][r] + wxf + vkb[(size_t)jidx * E_DIM + f];
            c = fmaxf(c, 0.f);
            float sv = state[(size_t)(m0 + w * 16 + rl) * E_DIM + f]; // L2-hot re-read
            float t = fmaf(gate[r], c, sv);
            acc[nt][r] = t;
            sumsq[r] += t * t;
        }
    }
    float rn[4];
#pragma unroll
    for (int r = 0; r < 4; ++r) {
        float s2 = sumsq[r];
        s2 += __shfl_xor(s2, 1);
        s2 += __shfl_xor(s2, 2);
        s2 += __shfl_xor(s2, 4);
        s2 += __shfl_xor(s2, 8);
        rn[r] = 1.f / (sqrtf(s2) + 1e-8f);
    }
#pragma unroll
    for (int nt = 0; nt < 16; ++nt)
#pragma unroll
        for (int r = 0; r < 4; ++r)
            out[(size_t)(m0 + w * 16 + quad * 4 + r) * E_DIM + nt * 16 + l15] =
                acc[nt][r] * rn[r];
}

extern "C" void kernel_launch(void* const* d_in, const int* in_sizes, int n_in,
                              void* d_out, int out_size, void* d_ws, size_t ws_size,
                              hipStream_t stream) {
    const float* x     = (const float*)d_in[0];
    const float* state = (const float*)d_in[1];
    const float* keys  = (const float*)d_in[2];
    const float* U     = (const float*)d_in[3];
    const float* V     = (const float*)d_in[4];
    const float* W     = (const float*)d_in[5];
    const float* bias  = (const float*)d_in[6];
    float* out = (float*)d_out;

    float* wsf = (float*)d_ws;
    float* wx  = wsf;                                   // 4096*256 fp32 = 4 MB
    float* xk  = wsf + (size_t)B_DIM * E_DIM;           // 4096*32  fp32 = 512 KB
    float* vkb = xk + (size_t)B_DIM * J_DIM;            // 32*256   fp32 = 32 KB
    bf16_t* Ubf = (bf16_t*)(vkb + (size_t)J_DIM * E_DIM); // 256*256 bf16 = 128 KB

    xkvkb_kernel<<<608, 256, 0, stream>>>(x, keys, U, V, bias, xk, vkb, Ubf);
    wx_kernel<<<256, 256, 0, stream>>>(x, W, wx);
    memcell_kernel<<<M_DIM / BM, 256, 0, stream>>>(x, state, Ubf, wx, xk, vkb, out);
}

// Round 12
// 299.595 us; speedup vs baseline: 2.3132x; 1.1869x over previous
//
#include <hip/hip_runtime.h>
#include <hip/hip_bf16.h>

typedef __bf16 bf16_t;
typedef __attribute__((ext_vector_type(8))) __bf16 bf16x8;
typedef __attribute__((ext_vector_type(4))) float f32x4;

#define E_DIM 256
#define J_DIM 32
#define B_DIM 4096
#define M_DIM (B_DIM * J_DIM)
#define BM 64
#define BK 32
#define LDA 40   // bf16: BK + 8 pad (16B-aligned, spreads banks)
#define LDB 40

#define XK_LDA (E_DIM + 4)  // fp32 xk tile pad: 32-way -> 4-way bank alias

// load 8 consecutive fp32, convert to bf16x8 (RNE)
__device__ inline bf16x8 cvt8(const float* __restrict__ p) {
    f32x4 a = *(const f32x4*)p;
    f32x4 b = *(const f32x4*)(p + 4);
    bf16x8 r;
    r[0] = (bf16_t)a[0]; r[1] = (bf16_t)a[1]; r[2] = (bf16_t)a[2]; r[3] = (bf16_t)a[3];
    r[4] = (bf16_t)b[0]; r[5] = (bf16_t)b[1]; r[6] = (bf16_t)b[2]; r[7] = (bf16_t)b[3];
    return r;
}

// ---------------------------------------------------------------------------
// fused prep: [0,512): xk[b][j] = <x_b,k_j>   [512,544): vkb[j][f]
//             [544,800): wx tiles (r6 wx_kernel body, 64x64, full-chip shape)
// ---------------------------------------------------------------------------
__global__ __launch_bounds__(256) void prep_kernel(
    const float* __restrict__ x, const float* __restrict__ keys,
    const float* __restrict__ V, const float* __restrict__ bias,
    const float* __restrict__ W,
    float* __restrict__ xk, float* __restrict__ vkb, float* __restrict__ wx) {
    __shared__ __align__(16) float smem[(J_DIM + 8) * XK_LDA];   // 41.6 KB
    int tid = threadIdx.x, bid = blockIdx.x;
    if (bid < 512) {
        float* sK = smem;                          // [32][XK_LDA]
        float* sX = smem + J_DIM * XK_LDA;         // [8][XK_LDA]
        int b0 = bid * 8;
#pragma unroll
        for (int it = 0; it < 8; ++it) {
            int t = it * 256 + tid;
            int r = t >> 6, c = (t & 63) * 4;
            *(f32x4*)(sK + r * XK_LDA + c) = *(const f32x4*)(keys + (size_t)r * E_DIM + c);
        }
#pragma unroll
        for (int it = 0; it < 2; ++it) {
            int t = it * 256 + tid;
            int r = t >> 6, c = (t & 63) * 4;
            *(f32x4*)(sX + r * XK_LDA + c) =
                *(const f32x4*)(x + (size_t)b0 * E_DIM + (size_t)r * E_DIM + c);
        }
        __syncthreads();
        int j = tid & 31, bl = tid >> 5;
        float acc = 0.f;
        for (int e = 0; e < E_DIM; e += 4) {
            f32x4 xv = *(const f32x4*)(sX + bl * XK_LDA + e);
            f32x4 kv = *(const f32x4*)(sK + j * XK_LDA + e);
#pragma unroll
            for (int i = 0; i < 4; ++i) acc += xv[i] * kv[i];
        }
        xk[(size_t)(b0 + bl) * J_DIM + j] = acc;
    } else if (bid < 544) {
        int j = bid - 512, f = tid;
        float* sk = smem;
        sk[f] = keys[(size_t)j * E_DIM + f];
        __syncthreads();
        float acc = bias[f];
        for (int e = 0; e < E_DIM; e += 4) {
            f32x4 vv = *(const f32x4*)(V + (size_t)f * E_DIM + e);
#pragma unroll
            for (int i = 0; i < 4; ++i) acc += vv[i] * sk[e + i];
        }
        vkb[(size_t)j * E_DIM + f] = acc;
    } else {
        // wx: alias smem (sA 1280 floats, sBw 1280 floats; both 16B-aligned)
        bf16_t (*sA)[LDA]  = (bf16_t (*)[LDA])smem;
        bf16_t (*sBw)[LDB] = (bf16_t (*)[LDB])(smem + 1280);
        int w = tid >> 6, lane = tid & 63, quad = lane >> 4, l15 = lane & 15;
        int wbid = bid - 544;
        int m0 = (wbid >> 2) * 64, n0 = (wbid & 3) * 64;
        f32x4 acc[4];
#pragma unroll
        for (int nt = 0; nt < 4; ++nt)
#pragma unroll
            for (int r = 0; r < 4; ++r) acc[nt][r] = 0.f;
        int arow = tid >> 2, akk = (tid & 3) * 8;
        for (int kc = 0; kc < 8; ++kc) {
            int k0 = kc * BK;
            __syncthreads();
            *(bf16x8*)(&sA[arow][akk]) = cvt8(x + (size_t)(m0 + arow) * E_DIM + k0 + akk);
            *(bf16x8*)(&sBw[arow][akk]) = cvt8(W + (size_t)(n0 + arow) * E_DIM + k0 + akk);
            __syncthreads();
            bf16x8 af = *(const bf16x8*)(&sA[w * 16 + l15][quad * 8]);
#pragma unroll
            for (int nt = 0; nt < 4; ++nt) {
                bf16x8 bfr = *(const bf16x8*)(&sBw[nt * 16 + l15][quad * 8]);
                acc[nt] = __builtin_amdgcn_mfma_f32_16x16x32_bf16(af, bfr, acc[nt], 0, 0, 0);
            }
        }
#pragma unroll
        for (int nt = 0; nt < 4; ++nt)
#pragma unroll
            for (int r = 0; r < 4; ++r)
                wx[(size_t)(m0 + w * 16 + quad * 4 + r) * E_DIM + n0 + nt * 16 + l15] =
                    acc[nt][r];
    }
}

// ---------------------------------------------------------------------------
// main: r0/r6 loop with ONE strict work-removal — the gate dot is accumulated
// in the STAGE phase from the already-loaded state registers (a,b), so the
// fp32 sAf tile (8 LDS writes + 16 LDS reads per thread per kc) is deleted.
// Reduction: the 4 threads staging one row are consecutive lanes (4r..4r+3)
// -> __shfl_xor(1),(2); epilogue pulls gate from lane rl*4.
// Global loads, cvt, sA/sB staging, barriers, MFMA phase: byte-identical.
// ---------------------------------------------------------------------------
__global__ __launch_bounds__(256) void memcell_kernel(
    const float* __restrict__ x, const float* __restrict__ state,
    const float* __restrict__ U, const float* __restrict__ wx,
    const float* __restrict__ xk, const float* __restrict__ vkb,
    float* __restrict__ out) {
    __shared__ __align__(16) bf16_t sA[BM][LDA];
    __shared__ __align__(16) bf16_t sB[E_DIM][LDB];
    __shared__ __align__(16) float sXf[2][E_DIM];   // fp32 x rows (gate dot)
    int tid = threadIdx.x;
    int w = tid >> 6, lane = tid & 63, quad = lane >> 4, l15 = lane & 15;
    int m0 = blockIdx.x * BM;
    int b0 = m0 >> 5;                       // block covers b0, b0+1
    f32x4 acc[16];
#pragma unroll
    for (int nt = 0; nt < 16; ++nt)
#pragma unroll
        for (int r = 0; r < 4; ++r) acc[nt][r] = 0.f;
    float gpart = 0.f;
    if (tid < 64) {                          // stage the 2 x-rows (fp32)
        int bb = tid >> 5, p = tid & 31;
        f32x4 xa = *(const f32x4*)(x + (size_t)(b0 + bb) * E_DIM + p * 8);
        f32x4 xb = *(const f32x4*)(x + (size_t)(b0 + bb) * E_DIM + p * 8 + 4);
        *(f32x4*)(&sXf[bb][p * 8]) = xa;
        *(f32x4*)(&sXf[bb][p * 8 + 4]) = xb;
    }
    int arow = tid >> 2, akk = (tid & 3) * 8;
    const float* xrow = &sXf[arow >> 5][0];  // x row matching this state row
    for (int kc = 0; kc < 8; ++kc) {
        int k0 = kc * BK;
        __syncthreads();
        {   // stage state tile: bf16 for MFMA + gate-dot partial from regs
            const float* sp = state + (size_t)(m0 + arow) * E_DIM + k0 + akk;
            f32x4 a = *(const f32x4*)sp;
            f32x4 b = *(const f32x4*)(sp + 4);
            bf16x8 r;
            r[0] = (bf16_t)a[0]; r[1] = (bf16_t)a[1]; r[2] = (bf16_t)a[2]; r[3] = (bf16_t)a[3];
            r[4] = (bf16_t)b[0]; r[5] = (bf16_t)b[1]; r[6] = (bf16_t)b[2]; r[7] = (bf16_t)b[3];
            *(bf16x8*)(&sA[arow][akk]) = r;
#pragma unroll
            for (int i = 0; i < 4; ++i) gpart += a[i] * xrow[k0 + akk + i];
#pragma unroll
            for (int i = 0; i < 4; ++i) gpart += b[i] * xrow[k0 + akk + 4 + i];
        }
#pragma unroll
        for (int it = 0; it < 4; ++it) {
            int t = it * 256 + tid;
            int n = t >> 2, kk = (t & 3) * 8;
            *(bf16x8*)(&sB[n][kk]) = cvt8(U + (size_t)n * E_DIM + k0 + kk);
        }
        __syncthreads();
        // A-frag: row = w*16+l15 (wave owns 16 full rows), k = k0 + quad*8 + j
        bf16x8 af = *(const bf16x8*)(&sA[w * 16 + l15][quad * 8]);
#pragma unroll
        for (int nt = 0; nt < 16; ++nt) {
            bf16x8 bfr = *(const bf16x8*)(&sB[nt * 16 + l15][quad * 8]);
            acc[nt] = __builtin_amdgcn_mfma_f32_16x16x32_bf16(af, bfr, acc[nt], 0, 0, 0);
        }
    }
    // reduce gate dot across the 4 threads sharing a row (consecutive lanes)
    gpart += __shfl_xor(gpart, 1);
    gpart += __shfl_xor(gpart, 2);
    int bw = b0 + (w >> 1);                 // one b per wave
    int jrow = (w & 1) * 16 + (arow & 15);  // j index of this thread's row
    float garg = gpart + xk[(size_t)bw * J_DIM + jrow];
    float gv = 1.f / (1.f + expf(-garg));
    float gate[4];
#pragma unroll
    for (int r = 0; r < 4; ++r) gate[r] = __shfl(gv, (quad * 4 + r) * 4);
    // epilogue: C/D layout row = quad*4+r, col = nt*16+l15
    float sumsq[4] = {0.f, 0.f, 0.f, 0.f};
    const float* wxrow = wx + (size_t)bw * E_DIM;
#pragma unroll
    for (int nt = 0; nt < 16; ++nt) {
        int f = nt * 16 + l15;
        float wxf = wxrow[f];
#pragma unroll
        for (int r = 0; r < 4; ++r) {
            int rl = quad * 4 + r;
            int jidx = (w & 1) * 16 + rl;
            float c = acc[nt][r] + wxf + vkb[(size_t)jidx * E_DIM + f];
            c = fmaxf(c, 0.f);
            float sv = state[(size_t)(m0 + w * 16 + rl) * E_DIM + f]; // L2-hot re-read
            float t = fmaf(gate[r], c, sv);
            acc[nt][r] = t;
            sumsq[r] += t * t;
        }
    }
    float rn[4];
#pragma unroll
    for (int r = 0; r < 4; ++r) {
        float s2 = sumsq[r];
        s2 += __shfl_xor(s2, 1);
        s2 += __shfl_xor(s2, 2);
        s2 += __shfl_xor(s2, 4);
        s2 += __shfl_xor(s2, 8);
        rn[r] = 1.f / (sqrtf(s2) + 1e-8f);
    }
#pragma unroll
    for (int nt = 0; nt < 16; ++nt)
#pragma unroll
        for (int r = 0; r < 4; ++r)
            out[(size_t)(m0 + w * 16 + quad * 4 + r) * E_DIM + nt * 16 + l15] =
                acc[nt][r] * rn[r];
}

extern "C" void kernel_launch(void* const* d_in, const int* in_sizes, int n_in,
                              void* d_out, int out_size, void* d_ws, size_t ws_size,
                              hipStream_t stream) {
    const float* x     = (const float*)d_in[0];
    const float* state = (const float*)d_in[1];
    const float* keys  = (const float*)d_in[2];
    const float* U     = (const float*)d_in[3];
    const float* V     = (const float*)d_in[4];
    const float* W     = (const float*)d_in[5];
    const float* bias  = (const float*)d_in[6];
    float* out = (float*)d_out;

    float* wsf = (float*)d_ws;
    float* wx  = wsf;                                   // 4096*256 fp32 = 4 MB
    float* xk  = wsf + (size_t)B_DIM * E_DIM;           // 4096*32  fp32 = 512 KB
    float* vkb = xk + (size_t)B_DIM * J_DIM;            // 32*256   fp32 = 32 KB

    prep_kernel<<<800, 256, 0, stream>>>(x, keys, V, bias, W, xk, vkb, wx);
    memcell_kernel<<<M_DIM / BM, 256, 0, stream>>>(x, state, U, wx, xk, vkb, out);
}